// Round 13
// baseline (605.061 us; speedup 1.0000x reference)
//
#include <hip/hip_runtime.h>
#include <hip/hip_bf16.h>
#include <stdint.h>

#define B_ 16
#define T_ 30
#define H_ 64
#define W_ 44
#define HW_ (H_*W_)            // 2816
#define THW_ (T_*HW_)          // 84480

// padded transposed layout: xt[b][half][t:30][hp:66][wp:46][32 ic] bf16
#define HP_ 66
#define WP_ 46
#define PPLANE_ (HP_*WP_)      // 3036
#define PPOS_ (T_*PPLANE_)     // 91080 pos per (b,half)

// conv tiling: 256 thr (4 waves = 4 t-slices), out tile 4t x 8h x 16w, 64 oc
#define NS 1080                // 6z x 10y x 18x staged rows (64 B each per K-half)

// LDS 16B-chunk swizzle (validated R3/R10: SQ_LDS_BANK_CONFLICT = 0)
#define SWZ(v) (((v) >> 1) & 3)

typedef __bf16 bf16x8 __attribute__((ext_vector_type(8)));
typedef float f32x4 __attribute__((ext_vector_type(4)));

static __device__ __forceinline__ short f2bf(float f) {
    __hip_bfloat16 h = __float2bfloat16(f);
    union { __hip_bfloat16 b; short s; } u; u.b = h; return u.s;
}

static __device__ __forceinline__ void gload_lds16(const short* g, short* l) {
    __builtin_amdgcn_global_load_lds((const __attribute__((address_space(1))) void*)g,
                                     (__attribute__((address_space(3))) void*)l, 16, 0, 0);
}

// ---------------- kernel 0: transpose + fused GAP ----------------
__global__ __launch_bounds__(256) void transpose_kernel(const float* __restrict__ x,
                                                        short* __restrict__ xt,
                                                        float* __restrict__ gap) {
    __shared__ short lb[64*52];
    __shared__ float gsum[64];
    int blk = blockIdx.x;
    int b = blk / (T_*HP_);
    int r = blk - b*(T_*HP_);
    int t = r / HP_;
    int hp = r - t*HP_;
    int tid = threadIdx.x;
    bool interior = (hp >= 1) && (hp <= H_);
    float rsum = 0.f;
    {
        int ic = tid >> 2, g = tid & 3;
        if (interior) {
            int h = hp - 1;
            const float4* row = (const float4*)(x + ((size_t)(b*64 + ic)*T_ + t)*HW_ + h*W_);
            #pragma unroll
            for (int q = g; q < 11; q += 4) {
                float4 v = row[q];
                short4 s4;
                s4.x = f2bf(v.x); s4.y = f2bf(v.y); s4.z = f2bf(v.z); s4.w = f2bf(v.w);
                *(short4*)&lb[ic*52 + q*4] = s4;
                rsum += (v.x + v.y) + (v.z + v.w);
            }
        }
        rsum += __shfl_xor(rsum, 1);
        rsum += __shfl_xor(rsum, 2);
        if ((tid & 3) == 0) gsum[ic] = rsum;
    }
    __syncthreads();
    if (interior && tid < 64)
        atomicAdd(&gap[b*64 + tid], gsum[tid] * (1.0f / THW_));
    for (int e = tid; e < WP_*16; e += 256) {
        int wp = e >> 4, i4 = (e & 15) * 4;
        short4 s4 = make_short4(0,0,0,0);
        if (interior && wp >= 1 && wp <= W_) {
            int w = wp - 1;
            s4.x = lb[(i4+0)*52 + w];
            s4.y = lb[(i4+1)*52 + w];
            s4.z = lb[(i4+2)*52 + w];
            s4.w = lb[(i4+3)*52 + w];
        }
        size_t pos = (size_t)t*PPLANE_ + hp*WP_ + wp;
        short* dst = xt + ((size_t)(b*2 + (i4 >> 5))*PPOS_ + pos)*32 + (i4 & 31);
        *(short4*)dst = s4;
    }
}

// ---------------- kernel 2: reduce FC + fc1 + sigmoid ----------------
__global__ __launch_bounds__(256) void fc_kernel(const float* __restrict__ gap,
        const float* __restrict__ w_reduce, const float* __restrict__ b_reduce,
        const float* __restrict__ w_fc1, const float* __restrict__ b_fc1,
        float* __restrict__ h_out) {
    __shared__ float gl[256];
    int t = threadIdx.x;
    {
        int b = t >> 4, j = t & 15;
        float a = b_reduce[j];
        #pragma unroll
        for (int c = 0; c < 64; ++c) a += gap[b*64 + c] * w_reduce[j*64 + c];
        gl[b*16 + j] = a;
    }
    __syncthreads();
    for (int idx = t; idx < 2048; idx += 256) {
        int b = idx >> 7, j = idx & 127;
        float v = b_fc1[j];
        #pragma unroll
        for (int i = 0; i < 16; ++i) v += gl[b*16 + i] * w_fc1[j*16 + i];
        h_out[idx] = 1.0f / (1.0f + expf(-v));
    }
}

// ---------------- kernel 3: dynamic weights bf16 (+ zero block) ----------------
__global__ __launch_bounds__(256) void wdyn_kernel(const float* __restrict__ w_fc2,
        const float* __restrict__ h, short* __restrict__ wdyn, short* __restrict__ zblk) {
    if (blockIdx.x == 0 && threadIdx.x < 128) zblk[threadIdx.x] = 0;
    int b = blockIdx.x / 27, tap = blockIdx.x % 27;
    short* dst = wdyn + ((size_t)b*27 + tap) * 4096;
    for (int e = threadIdx.x; e < 4096; e += 256) {
        int oc = e >> 6, ic = e & 63;
        float wv = w_fc2[(oc*64 + ic)*27 + tap];
        float hv = h[b*128 + 2*oc + (ic >> 5)];
        dst[e] = f2bf(wv * hv);
    }
}

#define MF4(J, BV) do {                                                \
    acc[0][J] = __builtin_amdgcn_mfma_f32_16x16x32_bf16(a0, BV, acc[0][J], 0, 0, 0); \
    acc[1][J] = __builtin_amdgcn_mfma_f32_16x16x32_bf16(a1, BV, acc[1][J], 0, 0, 0); \
    acc[2][J] = __builtin_amdgcn_mfma_f32_16x16x32_bf16(a2, BV, acc[2][J], 0, 0, 0); \
    acc[3][J] = __builtin_amdgcn_mfma_f32_16x16x32_bf16(a3, BV, acc[3][J], 0, 0, 0); \
} while (0)

#define MFMA32(B0,B1,B2,B3,B4,B5,B6,B7) do {                           \
    __builtin_amdgcn_s_setprio(1);                                     \
    MF4(0,B0); MF4(1,B1); MF4(2,B2); MF4(3,B3);                        \
    MF4(4,B4); MF4(5,B5); MF4(6,B6); MF4(7,B7);                        \
    __builtin_amdgcn_s_setprio(0);                                     \
} while (0)

#define AREAD() do {                                                   \
    int _cw = (kg ^ SWZ(ln)) * 8;                                      \
    a0 = *(const bf16x8*)&wb[(ln     )*32 + _cw];                      \
    a1 = *(const bf16x8*)&wb[(ln + 16)*32 + _cw];                      \
    a2 = *(const bf16x8*)&wb[(ln + 32)*32 + _cw];                      \
    a3 = *(const bf16x8*)&wb[(ln + 48)*32 + _cw];                      \
} while (0)

#define BROW(Y, DST) do {                                              \
    int _s = sbase + (Y)*18;                                           \
    DST = *(const bf16x8*)&xs[_s*32 + ((kg ^ SWZ(_s)) * 8)];           \
} while (0)

// publish wr -> wb between the two barriers (R10-proven rhythm)
#define PUBLISH() do {                                                 \
    __syncthreads();                                                   \
    *(uint4*)wdst = wr;                                                \
    __syncthreads();                                                   \
} while (0)

// ---------------- kernel 4: implicit-GEMM dynamic conv3d ----------------
// LDS-BW-bound fix: (kd,kw) super-steps with kh innermost; the 10 B-rows for a
// super-step are read once into registers and reused across 3 taps (22 LDS
// reads / 96 MFMAs vs 36 before) -> MFMA pipe becomes the limiter.
// acc[4][8]=128 AGPR + ~100 VGPR <= 256 -> 2 waves/SIMD; LDS 73,728B x2/CU.
__global__ __launch_bounds__(256, 2) void conv_kernel(const short* __restrict__ xt,
        const short* __restrict__ wdyn, const short* __restrict__ zblk,
        float* __restrict__ out) {
    __shared__ short xs[NS*32 + 256];  // 69,632 B (pad absorbs staging overrun)
    __shared__ short wb[2048];         //  4,096 B (one tap, one K-half)

    // XCD swizzle: 3072 blocks = 8 XCDs x 384 contiguous (3072 % 8 == 0)
    int bid = (blockIdx.x & 7) * 384 + (blockIdx.x >> 3);
    int b = bid / 192; int r = bid - b*192;
    int tzt = r / 24; r -= tzt*24;
    int tyt = r / 3;  int txt = r - tyt*3;
    int t0 = tzt*4, h0 = tyt*8, w0 = txt*16;

    int tid = threadIdx.x, wid = tid >> 6, lane = tid & 63;
    int ln = lane & 15, kg = lane >> 4;
    int l4 = lane >> 2, c = lane & 3;
    int tzw = wid;                               // wave = t-slice
    int woc = tid >> 2, wseg = tid & 3;          // weight staging role

    const short* wdb   = wdyn + (size_t)b * 27 * 4096;
    const short* wbase = wdb + woc*64 + wseg*8;
    short* wdst = wb + woc*32 + ((wseg ^ SWZ(woc)) * 8);

    f32x4 acc[4][8];
    #pragma unroll
    for (int mt = 0; mt < 4; ++mt)
        #pragma unroll
        for (int j = 0; j < 8; ++j) acc[mt][j] = f32x4{0.f, 0.f, 0.f, 0.f};

    auto stage_x = [&](int half) {               // 68 gload_lds over 4 waves
        const short* xbh = xt + (size_t)(b*2 + half) * PPOS_ * 32;
        #pragma unroll 2
        for (int ii = 0; ii < 17; ++ii) {
            int inst = wid*17 + ii;
            int s = inst*16 + l4;
            int z = s / 180; int rr2 = s - z*180;
            int y = rr2 / 18; int xx = rr2 - y*18;
            int t = t0 + z - 1;
            int seg = (c ^ SWZ(s)) * 8;
            const short* src = ((unsigned)t < (unsigned)T_)
                ? xbh + ((size_t)t*PPLANE_ + (h0+y)*WP_ + (w0+xx))*32 + seg
                : zblk + seg;
            gload_lds16(src, xs + inst*512);
        }
    };

    // prologue: stage xs half 0; prefetch tap-0 weights. First loop barrier's
    // implicit vmcnt(0) drains both before the first publish.
    stage_x(0);
    uint4 wr = *(const uint4*)(wbase);

    int kd = 0, kw = 0, hoff = 0;
    bf16x8 a0, a1, a2, a3;
    bf16x8 r0, r1, r2, r3, r4, r5, r6, r7, r8, r9;

    #pragma unroll 1
    for (int ss = 0; ss < 18; ++ss) {
        // next super-step coordinates (for the kh=2 prefetch)
        int nkw  = (kw == 2) ? 0 : kw + 1;
        int nkd  = (kw == 2) ? ((kd == 2) ? 0 : kd + 1) : kd;
        int nhoff = (kw == 2 && kd == 2) ? 32 : hoff;
        int sbase = (tzw + kd)*180 + kw + ln;
        int tb = kd*9 + kw;                      // tapid at kh=0

        // ---- kh = 0 ----
        PUBLISH();
        wr = *(const uint4*)(wbase + (tb + 3)*4096 + hoff);
        BROW(0, r0); BROW(1, r1); BROW(2, r2); BROW(3, r3); BROW(4, r4);
        BROW(5, r5); BROW(6, r6); BROW(7, r7); BROW(8, r8); BROW(9, r9);
        AREAD();
        MFMA32(r0, r1, r2, r3, r4, r5, r6, r7);
        // ---- kh = 1 ----
        PUBLISH();
        wr = *(const uint4*)(wbase + (tb + 6)*4096 + hoff);
        AREAD();
        MFMA32(r1, r2, r3, r4, r5, r6, r7, r8);
        // ---- kh = 2 ----
        PUBLISH();
        if (ss < 17)
            wr = *(const uint4*)(wbase + (nkd*9 + nkw)*4096 + nhoff);
        AREAD();
        MFMA32(r2, r3, r4, r5, r6, r7, r8, r9);

        if (ss == 8) {                           // half transition
            __syncthreads();                     // xs(0) reads complete
            stage_x(1);
            asm volatile("s_waitcnt vmcnt(0)" ::: "memory");
            __builtin_amdgcn_s_barrier();        // xs(1) landed everywhere
        }
        kd = nkd; kw = nkw; hoff = nhoff;
    }

    // epilogue: D layout col=lane&15 (pos=w), row=(lane>>4)*4+ri (oc)
    int t = t0 + tzw;
    int wv = w0 + ln;
    if (t < T_ && wv < W_) {
        #pragma unroll
        for (int mt = 0; mt < 4; ++mt) {
            size_t obase = ((size_t)(b*64 + mt*16 + kg*4) * T_ + t) * HW_;
            #pragma unroll
            for (int j = 0; j < 8; ++j) {
                float* o = out + obase + (h0 + j)*W_ + wv;
                #pragma unroll
                for (int ri = 0; ri < 4; ++ri)
                    o[(size_t)ri * THW_] = acc[mt][j][ri];
            }
        }
    }
}

extern "C" void kernel_launch(void* const* d_in, const int* in_sizes, int n_in,
                              void* d_out, int out_size, void* d_ws, size_t ws_size,
                              hipStream_t stream) {
    const float* x        = (const float*)d_in[0];
    const float* w_reduce = (const float*)d_in[1];
    const float* b_reduce = (const float*)d_in[2];
    const float* w_fc1    = (const float*)d_in[3];
    const float* b_fc1    = (const float*)d_in[4];
    const float* w_fc2    = (const float*)d_in[5];
    float* out = (float*)d_out;

    // ws layout: gap 4KB | h 8KB | wdyn 3.375MB | zblk 256B | xt 186.5MB (+slack)
    float* gap  = (float*)d_ws;
    float* h    = gap + 1024;
    short* wdyn = (short*)(h + 2048);
    short* zblk = wdyn + (size_t)B_*27*4096;
    short* xt   = zblk + 128;

    hipMemsetAsync(gap, 0, 1024*sizeof(float), stream);   // atomic accumulator
    transpose_kernel<<<B_*T_*HP_, 256, 0, stream>>>(x, xt, gap);
    fc_kernel       <<<1,         256, 0, stream>>>(gap, w_reduce, b_reduce, w_fc1, b_fc1, h);
    wdyn_kernel     <<<B_*27,     256, 0, stream>>>(w_fc2, h, wdyn, zblk);
    conv_kernel     <<<B_*192,    256, 0, stream>>>(xt, wdyn, zblk, out);
}

// Round 14
// 524.880 us; speedup vs baseline: 1.1528x; 1.1528x over previous
//
#include <hip/hip_runtime.h>
#include <hip/hip_bf16.h>
#include <stdint.h>

#define B_ 16
#define T_ 30
#define H_ 64
#define W_ 44
#define HW_ (H_*W_)            // 2816
#define THW_ (T_*HW_)          // 84480

// padded transposed layout: xt[b][half][t:30][hp:66][wp:46][32 ic] bf16
#define HP_ 66
#define WP_ 46
#define PPLANE_ (HP_*WP_)      // 3036
#define PPOS_ (T_*PPLANE_)     // 91080 pos per (b,half)

// conv tiling: 256 thr (4 waves), out tile 2t x 8h x 16w = 256 pos, 64 oc
#define NS2 720                // 4z x 10y x 18x staged rows (64 B each per K-half)

// LDS 16B-chunk swizzle (validated R3/R10: SQ_LDS_BANK_CONFLICT = 0)
#define SWZ(v) (((v) >> 1) & 3)

typedef __bf16 bf16x8 __attribute__((ext_vector_type(8)));
typedef float f32x4 __attribute__((ext_vector_type(4)));

static __device__ __forceinline__ short f2bf(float f) {
    __hip_bfloat16 h = __float2bfloat16(f);
    union { __hip_bfloat16 b; short s; } u; u.b = h; return u.s;
}

static __device__ __forceinline__ void gload_lds16(const short* g, short* l) {
    __builtin_amdgcn_global_load_lds((const __attribute__((address_space(1))) void*)g,
                                     (__attribute__((address_space(3))) void*)l, 16, 0, 0);
}

// ---------------- kernel 0: transpose + fused GAP ----------------
__global__ __launch_bounds__(256) void transpose_kernel(const float* __restrict__ x,
                                                        short* __restrict__ xt,
                                                        float* __restrict__ gap) {
    __shared__ short lb[64*52];
    __shared__ float gsum[64];
    int blk = blockIdx.x;
    int b = blk / (T_*HP_);
    int r = blk - b*(T_*HP_);
    int t = r / HP_;
    int hp = r - t*HP_;
    int tid = threadIdx.x;
    bool interior = (hp >= 1) && (hp <= H_);
    float rsum = 0.f;
    {
        int ic = tid >> 2, g = tid & 3;
        if (interior) {
            int h = hp - 1;
            const float4* row = (const float4*)(x + ((size_t)(b*64 + ic)*T_ + t)*HW_ + h*W_);
            #pragma unroll
            for (int q = g; q < 11; q += 4) {
                float4 v = row[q];
                short4 s4;
                s4.x = f2bf(v.x); s4.y = f2bf(v.y); s4.z = f2bf(v.z); s4.w = f2bf(v.w);
                *(short4*)&lb[ic*52 + q*4] = s4;
                rsum += (v.x + v.y) + (v.z + v.w);
            }
        }
        rsum += __shfl_xor(rsum, 1);
        rsum += __shfl_xor(rsum, 2);
        if ((tid & 3) == 0) gsum[ic] = rsum;
    }
    __syncthreads();
    if (interior && tid < 64)
        atomicAdd(&gap[b*64 + tid], gsum[tid] * (1.0f / THW_));
    for (int e = tid; e < WP_*16; e += 256) {
        int wp = e >> 4, i4 = (e & 15) * 4;
        short4 s4 = make_short4(0,0,0,0);
        if (interior && wp >= 1 && wp <= W_) {
            int w = wp - 1;
            s4.x = lb[(i4+0)*52 + w];
            s4.y = lb[(i4+1)*52 + w];
            s4.z = lb[(i4+2)*52 + w];
            s4.w = lb[(i4+3)*52 + w];
        }
        size_t pos = (size_t)t*PPLANE_ + hp*WP_ + wp;
        short* dst = xt + ((size_t)(b*2 + (i4 >> 5))*PPOS_ + pos)*32 + (i4 & 31);
        *(short4*)dst = s4;
    }
}

// ---------------- kernel 2: reduce FC + fc1 + sigmoid ----------------
__global__ __launch_bounds__(256) void fc_kernel(const float* __restrict__ gap,
        const float* __restrict__ w_reduce, const float* __restrict__ b_reduce,
        const float* __restrict__ w_fc1, const float* __restrict__ b_fc1,
        float* __restrict__ h_out) {
    __shared__ float gl[256];
    int t = threadIdx.x;
    {
        int b = t >> 4, j = t & 15;
        float a = b_reduce[j];
        #pragma unroll
        for (int c = 0; c < 64; ++c) a += gap[b*64 + c] * w_reduce[j*64 + c];
        gl[b*16 + j] = a;
    }
    __syncthreads();
    for (int idx = t; idx < 2048; idx += 256) {
        int b = idx >> 7, j = idx & 127;
        float v = b_fc1[j];
        #pragma unroll
        for (int i = 0; i < 16; ++i) v += gl[b*16 + i] * w_fc1[j*16 + i];
        h_out[idx] = 1.0f / (1.0f + expf(-v));
    }
}

// ---------------- kernel 3: dynamic weights bf16 (+ zero block) ----------------
__global__ __launch_bounds__(256) void wdyn_kernel(const float* __restrict__ w_fc2,
        const float* __restrict__ h, short* __restrict__ wdyn, short* __restrict__ zblk) {
    if (blockIdx.x == 0 && threadIdx.x < 128) zblk[threadIdx.x] = 0;
    int b = blockIdx.x / 27, tap = blockIdx.x % 27;
    short* dst = wdyn + ((size_t)b*27 + tap) * 4096;
    for (int e = threadIdx.x; e < 4096; e += 256) {
        int oc = e >> 6, ic = e & 63;
        float wv = w_fc2[(oc*64 + ic)*27 + tap];
        float hv = h[b*128 + 2*oc + (ic >> 5)];
        dst[e] = f2bf(wv * hv);
    }
}

#define MF4(J, BV) do {                                                \
    acc[0][J] = __builtin_amdgcn_mfma_f32_16x16x32_bf16(a0, BV, acc[0][J], 0, 0, 0); \
    acc[1][J] = __builtin_amdgcn_mfma_f32_16x16x32_bf16(a1, BV, acc[1][J], 0, 0, 0); \
    acc[2][J] = __builtin_amdgcn_mfma_f32_16x16x32_bf16(a2, BV, acc[2][J], 0, 0, 0); \
    acc[3][J] = __builtin_amdgcn_mfma_f32_16x16x32_bf16(a3, BV, acc[3][J], 0, 0, 0); \
} while (0)

#define MFMA16(B0,B1,B2,B3) do {                                       \
    __builtin_amdgcn_s_setprio(1);                                     \
    MF4(0,B0); MF4(1,B1); MF4(2,B2); MF4(3,B3);                        \
    __builtin_amdgcn_s_setprio(0);                                     \
} while (0)

#define AREAD() do {                                                   \
    int _cw = (kg ^ SWZ(ln)) * 8;                                      \
    a0 = *(const bf16x8*)&wb[(ln     )*32 + _cw];                      \
    a1 = *(const bf16x8*)&wb[(ln + 16)*32 + _cw];                      \
    a2 = *(const bf16x8*)&wb[(ln + 32)*32 + _cw];                      \
    a3 = *(const bf16x8*)&wb[(ln + 48)*32 + _cw];                      \
} while (0)

#define BROW(M, DST) do {                                              \
    int _s = sbro + (M)*18;                                            \
    DST = *(const bf16x8*)&xs[_s*32 + ((kg ^ SWZ(_s)) * 8)];           \
} while (0)

// publish wr -> wb between the two barriers (R10/R12-proven rhythm)
#define PUBLISH() do {                                                 \
    __syncthreads();                                                   \
    *(uint4*)wdst = wr;                                                \
    __syncthreads();                                                   \
} while (0)

// ---------------- kernel 4: implicit-GEMM dynamic conv3d ----------------
// R12's champion structure (3 blocks/CU, acc[4][4], 2-barrier step) with
// (kd,kw) super-steps, kh innermost: 6 B-rows held in registers and reused
// across the 3 kh taps -> 18 ds_read_b128 per 48 MFMAs (was 24), less VALU.
__global__ __launch_bounds__(256, 3) void conv_kernel(const short* __restrict__ xt,
        const short* __restrict__ wdyn, const short* __restrict__ zblk,
        float* __restrict__ out) {
    __shared__ short xs[NS2*32];     // 46,080 B
    __shared__ short wb[2048];       //  4,096 B (one tap, one K-half)

    // XCD swizzle: 5760 blocks = 8 XCDs x 720 contiguous (5760 % 8 == 0)
    int bid = (blockIdx.x & 7) * 720 + (blockIdx.x >> 3);
    int b = bid / 360; int r = bid - b*360;
    int tzt = r / 24; r -= tzt*24;
    int tyt = r / 3;  int txt = r - tyt*3;
    int t0 = tzt*2, h0 = tyt*8, w0 = txt*16;

    int tid = threadIdx.x, wid = tid >> 6, lane = tid & 63;
    int ln = lane & 15, kg = lane >> 4;
    int l4 = lane >> 2, c = lane & 3;
    int tzw = wid & 1, hw4 = (wid >> 1) * 4;
    int woc = tid >> 2, wseg = tid & 3;          // weight staging role

    const short* wdb   = wdyn + (size_t)b * 27 * 4096;
    const short* wbase = wdb + woc*64 + wseg*8;
    short* wdst = wb + woc*32 + ((wseg ^ SWZ(woc)) * 8);

    f32x4 acc[4][4];
    #pragma unroll
    for (int mt = 0; mt < 4; ++mt)
        #pragma unroll
        for (int j = 0; j < 4; ++j) acc[mt][j] = f32x4{0.f, 0.f, 0.f, 0.f};

    auto stage_x = [&](int half) {               // 45 gload_lds over 4 waves
        const short* xbh = xt + (size_t)(b*2 + half) * PPOS_ * 32;
        #pragma unroll
        for (int ii = 0; ii < 12; ++ii) {
            int inst = ii*4 + wid;
            if (inst < 45) {
                int s = inst*16 + l4;
                int z = s / 180; int rr = s - z*180;
                int y = rr / 18; int xx = rr - y*18;
                int t = t0 + z - 1;
                int seg = (c ^ SWZ(s)) * 8;
                const short* src = ((unsigned)t < (unsigned)T_)
                    ? xbh + ((size_t)t*PPLANE_ + (h0+y)*WP_ + (w0+xx))*32 + seg
                    : zblk + seg;
                gload_lds16(src, xs + inst*512);
            }
        }
    };

    // prologue: stage xs half 0, prefetch tap-0 weights; explicit barrier so
    // the super-step's leading B-row reads see staged xs.
    stage_x(0);
    uint4 wr = *(const uint4*)(wbase);
    asm volatile("s_waitcnt vmcnt(0)" ::: "memory");
    __builtin_amdgcn_s_barrier();

    bf16x8 a0, a1, a2, a3;
    bf16x8 r0, r1, r2, r3, r4, r5;

    #pragma unroll 1
    for (int ss = 0; ss < 18; ++ss) {
        int kdkw = ss - ((ss >= 9) ? 9 : 0);     // 0..8
        int kd = kdkw / 3, kw = kdkw - kd*3;
        int hoff = (ss >= 9) ? 32 : 0;
        int tb = kd*9 + kw;                      // tap at kh=0
        int sbro = (tzw + kd)*180 + hw4*18 + kw + ln;

        // 6 B-rows for this super-step (reused across the 3 kh taps)
        BROW(0, r0); BROW(1, r1); BROW(2, r2);
        BROW(3, r3); BROW(4, r4); BROW(5, r5);

        // ---- kh = 0 ----
        PUBLISH();
        wr = *(const uint4*)(wbase + (tb + 3)*4096 + hoff);
        AREAD();
        MFMA16(r0, r1, r2, r3);
        // ---- kh = 1 ----
        PUBLISH();
        wr = *(const uint4*)(wbase + (tb + 6)*4096 + hoff);
        AREAD();
        MFMA16(r1, r2, r3, r4);
        // ---- kh = 2 ----
        PUBLISH();
        if (ss < 17) {
            int nss = ss + 1;
            int nkdkw = nss - ((nss >= 9) ? 9 : 0);
            int nkd = nkdkw / 3, nkw = nkdkw - nkd*3;
            int nhoff = (nss >= 9) ? 32 : 0;
            wr = *(const uint4*)(wbase + (nkd*9 + nkw)*4096 + nhoff);
        }
        AREAD();
        MFMA16(r2, r3, r4, r5);

        if (ss == 8) {                           // half transition
            __syncthreads();                     // xs(0) reads complete
            stage_x(1);
            asm volatile("s_waitcnt vmcnt(0)" ::: "memory");
            __builtin_amdgcn_s_barrier();        // xs(1) landed everywhere
        }
    }

    // epilogue: D layout col=lane&15 (pos=w), row=(lane>>4)*4+ri (oc)
    int t = t0 + tzw;
    int wv = w0 + ln;
    if (wv < W_) {
        #pragma unroll
        for (int mt = 0; mt < 4; ++mt) {
            size_t obase = ((size_t)(b*64 + mt*16 + kg*4) * T_ + t) * HW_;
            #pragma unroll
            for (int j = 0; j < 4; ++j) {
                float* o = out + obase + (h0 + hw4 + j)*W_ + wv;
                #pragma unroll
                for (int ri = 0; ri < 4; ++ri)
                    o[(size_t)ri * THW_] = acc[mt][j][ri];
            }
        }
    }
}

extern "C" void kernel_launch(void* const* d_in, const int* in_sizes, int n_in,
                              void* d_out, int out_size, void* d_ws, size_t ws_size,
                              hipStream_t stream) {
    const float* x        = (const float*)d_in[0];
    const float* w_reduce = (const float*)d_in[1];
    const float* b_reduce = (const float*)d_in[2];
    const float* w_fc1    = (const float*)d_in[3];
    const float* b_fc1    = (const float*)d_in[4];
    const float* w_fc2    = (const float*)d_in[5];
    float* out = (float*)d_out;

    // ws layout: gap 4KB | h 8KB | wdyn 3.375MB | zblk 256B | xt 186.5MB (+slack)
    float* gap  = (float*)d_ws;
    float* h    = gap + 1024;
    short* wdyn = (short*)(h + 2048);
    short* zblk = wdyn + (size_t)B_*27*4096;
    short* xt   = zblk + 128;

    hipMemsetAsync(gap, 0, 1024*sizeof(float), stream);   // atomic accumulator
    transpose_kernel<<<B_*T_*HP_, 256, 0, stream>>>(x, xt, gap);
    fc_kernel       <<<1,         256, 0, stream>>>(gap, w_reduce, b_reduce, w_fc1, b_fc1, h);
    wdyn_kernel     <<<B_*27,     256, 0, stream>>>(w_fc2, h, wdyn, zblk);
    conv_kernel     <<<B_*360,    256, 0, stream>>>(xt, wdyn, zblk, out);
}